// Round 4
// baseline (71.339 us; speedup 1.0000x reference)
//
#include <hip/hip_runtime.h>

// Fixed by setup_inputs(): B=4, C=1, H=64, W=96 (P=6144).
// Hot path is specialized for C==1 && P==6144; anything else takes the
// slow-but-correct fallback.
#define B_FIXED 4
#define P_FIX   6144
#define BLOCK   256
#define NCH     (P_FIX / BLOCK)   // 24 register-resident chunks per thread
#define GRIDX   64                // blocks per sample == wave width
#define NJ      16                // j-range splits per i-tile
#define IBLK    2                 // i-rows per thread in the pair loop
#define NBIN    32                // key bins for counting sort (keys are 0..19)
#define PULL_MARGIN 0.5f
#define PUSH_MARGIN 1.0f

// ---- ws layout ------------------------------------------------------------
// Hot path : uint partial[B_FIXED*GRIDX*4] at offset 0 (4 KB):
//            slot s = b*GRIDX+bx, words {pull.f32, push.f32, ns.i32, n.i32}.
//            Words 0-2 stored RELAXED, word 3 (n) stored RELEASE; the
//            finalizer acquires on word 3 only (poison 0xAAAAAAAA has top
//            bit 1, all real values have top bit 0 -> single poll chain).
//            Agent-scope for cross-XCD visibility.
// Fallback : accF/nsI/npI at offset 4096 (memset'd; cold path only).

// ---- bool-mask encoding detection ----------------------------------------
// mode 0: int32 {0,1}; mode 1: uint8 {0,1}; mode 2: float32 {0,1.0f}
__device__ __forceinline__ bool read_fg(const void* mask, int mode, long idx) {
    if (mode == 0) return ((const int*)mask)[idx] != 0;
    if (mode == 1) return ((const unsigned char*)mask)[idx] != 0;
    return ((const float*)mask)[idx] != 0.0f;
}

__device__ __forceinline__ float relu_push(float diff) {   // (1 - |diff|)+
    return fmaxf(PUSH_MARGIN - fabsf(diff), 0.0f);
}
__device__ __forceinline__ float relu_pull(float diff) {   // (|diff| - 0.5)+
    return fmaxf(fabsf(diff) - PULL_MARGIN, 0.0f);
}

// ---- single fused kernel (C==1, P==6144) ----------------------------------
// grid (GRIDX, B). Each block redundantly compacts sample b's foreground
// pixels into its own LDS, COUNTING-SORTED BY KEY, computes its share of
// pair terms, stores its partial to a private ws slot (agent-scope).
// Block (0,0) then polls all 256 slots and writes the final loss.
// Deadlock-free: only block (0,0) waits; every other block exits.
//
// Sorted layout enables a select-free pair loop:
//   push = sum_all (1-d)+  -  sum_own-key-segment (1-d)+
//   pull = sum_own-key-segment (d-0.5)+
//   n_same = sum_g count_g^2   (from the histogram; reported ONCE by
//            thread 0 of block x==0 -- it is block-uniform and must not
//            enter the per-thread summing reduction more than once)
// Any foreground key outside [0,NBIN) flips a block-uniform badkey flag and
// the comparison-based loop runs instead (data is permuted, which is fine:
// pair sums are permutation-invariant).
__global__ __launch_bounds__(BLOCK)
void fused_all(const float* __restrict__ pred,
               const int*   __restrict__ gt,
               const void*  __restrict__ mask,
               unsigned int* __restrict__ partial,
               float* __restrict__ out) {
    __shared__ __align__(16) float sval[P_FIX];   // 24 KB (sorted values)
    __shared__ __align__(16) int   skey[P_FIX];   // 24 KB (sorted keys)
    __shared__ int   swdet[3 * (BLOCK / 64)];
    __shared__ int   shist[NBIN];   // per-key counts
    __shared__ int   sboff[NBIN];   // exclusive offsets (segment starts)
    __shared__ int   snext[NBIN];   // scatter cursors
    __shared__ int   smeta[3];      // n, ns_hist, badkey
    __shared__ float sredp[BLOCK / 64], sredq[BLOCK / 64];
    __shared__ int   sredn[BLOCK / 64];
    __shared__ float sloss[B_FIXED];

    const int tid  = threadIdx.x;
    const int b    = blockIdx.y;
    const int wv   = tid >> 6, lane = tid & 63;
    const long base = (long)b * P_FIX;

    // -- single load wave: ALL independent global reads issued together.
    //    * detection words: first P_FIX words of the mask buffer (in-bounds
    //      for all three candidate encodings).
    //    * own-sample BYTE view of the mask (byte idx < B*P -> in-bounds
    //      for every encoding; only used if mode==1).
    //    * pred, gt.
    const unsigned int*  mw = (const unsigned int*)mask;
    const unsigned char* m8 = (const unsigned char*)mask;
    float val[NCH]; int key[NCH];
    unsigned int detA = 0, detC = 0, detN = 0, fgb = 0;
    #pragma unroll
    for (int k = 0; k < NCH; ++k) {
        const int idx = k * BLOCK + tid;
        const unsigned int w = mw[idx];
        detA |= (w > 1u) ? 1u : 0u;
        detC |= (w != 0u && w != 0x3f800000u) ? 1u : 0u;
        detN |= w;
        fgb  |= (m8[base + idx] != 0) ? (1u << k) : 0u;
        val[k] = pred[base + idx];
        key[k] = gt[base + idx];
    }
    const int anyA = (__ballot(detA != 0u) != 0ull) ? 1 : 0;
    const int anyC = (__ballot(detC != 0u) != 0ull) ? 1 : 0;
    const int anyN = (__ballot(detN != 0u) != 0ull) ? 1 : 0;
    if (lane == 0) {
        swdet[wv * 3 + 0] = anyA;
        swdet[wv * 3 + 1] = anyC;
        swdet[wv * 3 + 2] = anyN;
    }
    if (tid < NBIN) shist[tid] = 0;
    if (tid == 0)   smeta[2] = 0;
    __syncthreads();
    int fA = 0, fC = 0, fN = 0;
    #pragma unroll
    for (int w = 0; w < BLOCK / 64; ++w) {
        fA |= swdet[w * 3 + 0]; fC |= swdet[w * 3 + 1]; fN |= swdet[w * 3 + 2];
    }
    const int mode = (!fA) ? 0 : (!fC ? 2 : 1);

    // -- foreground bits. Entirely-zero mask (fN==0) short-circuits (also
    //    avoids the word-view reload, which would be OOB on a byte buffer).
    unsigned int fgm;
    if (!fN) {
        fgm = 0;
    } else if (mode == 1) {
        fgm = fgb;
    } else if (mode == 0) {
        fgm = 0;
        #pragma unroll
        for (int k = 0; k < NCH; ++k)
            fgm |= (((const int*)mask)[base + k * BLOCK + tid] != 0) ? (1u << k) : 0u;
    } else {
        fgm = 0;
        #pragma unroll
        for (int k = 0; k < NCH; ++k)
            fgm |= (((const float*)mask)[base + k * BLOCK + tid] != 0.0f) ? (1u << k) : 0u;
    }

    // -- histogram over foreground keys (bins clamped via &31; exact keys
    //    kept in registers -> badkey path still sees true keys).
    unsigned int badbit = 0;
    #pragma unroll
    for (int k = 0; k < NCH; ++k) {
        if ((fgm >> k) & 1u) {
            const int kk = key[k];
            badbit |= (unsigned int)(kk < 0 || kk >= NBIN);
            atomicAdd(&shist[kk & (NBIN - 1)], 1);
        }
    }
    if (badbit) atomicOr(&smeta[2], 1);
    __syncthreads();

    // -- wave 0: 32-bin exclusive scan + n + ns = sum(count^2)
    if (wv == 0) {
        const int c = (lane < NBIN) ? shist[lane] : 0;
        int incl = c;
        #pragma unroll
        for (int off = 1; off < NBIN; off <<= 1) {
            const int u = __shfl_up(incl, off);
            if (lane >= off) incl += u;
        }
        int sq = c * c;
        #pragma unroll
        for (int off = 1; off < NBIN; off <<= 1)
            sq += __shfl_xor(sq, off);
        const int ntot = __shfl(incl, NBIN - 1);
        if (lane < NBIN) { sboff[lane] = incl - c; snext[lane] = incl - c; }
        if (lane == 0)   { smeta[0] = ntot; smeta[1] = sq; }
    }
    __syncthreads();
    const int n       = smeta[0];
    const int ns_hist = smeta[1];
    const int badkey  = smeta[2];

    // -- atomic-rank scatter into sorted LDS arrays (rank order within a
    //    bin is arbitrary -- pair sums don't care).
    #pragma unroll
    for (int k = 0; k < NCH; ++k) {
        if ((fgm >> k) & 1u) {
            const int r = atomicAdd(&snext[key[k] & (NBIN - 1)], 1);
            sval[r] = val[k]; skey[r] = key[k];
        }
    }
    __syncthreads();

    // -- pair loop: grid-stride over (i-tile, j-split) work items.
    //    i-tile = IBLK*BLOCK = 512 sorted rows; j-split = ~n/NJ columns.
    const int nti   = (n + IBLK * BLOCK - 1) / (IBLK * BLOCK);
    const int total = nti * NJ;
    float pull = 0.f, push = 0.f;
    int cnt = 0;                      // badkey path only

    for (int t = blockIdx.x; t < total; t += GRIDX) {
        const int it = t / NJ, jt = t - it * NJ;
        const int i0 = it * (IBLK * BLOCK) + tid;
        const int i1 = i0 + BLOCK;
        const bool v0 = i0 < n, v1 = i1 < n;
        const float pi0 = v0 ? sval[i0] : 1e30f;  // pad: push term -> 0
        const float pi1 = v1 ? sval[i1] : 1e30f;
        const int   ki0 = v0 ? skey[i0] : -2;     // pad: never 'same'
        const int   ki1 = v1 ? skey[i1] : -2;
        const int jlo = (jt == 0)      ? 0 : (int)(((long)jt * n / NJ) & ~3L);
        const int jhi = (jt == NJ - 1) ? n : (int)(((long)(jt + 1) * n / NJ) & ~3L);
        const int gve = jhi & ~3;                 // == jhi except last split

        if (!badkey) {
            // ---- select-free push-all over [jlo,jhi): 4 VALU per pair ----
            const float4* sv4 = (const float4*)sval;
            float q0 = 0.f, q1 = 0.f, q2 = 0.f, q3 = 0.f;
            #pragma unroll 2
            for (int g = (jlo >> 2); g < (gve >> 2); ++g) {
                const float4 v = sv4[g];
                q0 += relu_push(pi0 - v.x);
                q1 += relu_push(pi0 - v.y);
                q0 += relu_push(pi0 - v.z);
                q1 += relu_push(pi0 - v.w);
                q2 += relu_push(pi1 - v.x);
                q3 += relu_push(pi1 - v.y);
                q2 += relu_push(pi1 - v.z);
                q3 += relu_push(pi1 - v.w);
            }
            for (int j = gve; j < jhi; ++j) {     // scalar tail (last split)
                const float v = sval[j];
                q0 += relu_push(pi0 - v);
                q2 += relu_push(pi1 - v);
            }
            float q = (q0 + q1) + (q2 + q3);

            // ---- own-segment correction: pull + push fix-up --------------
            // Segment of key k is [sboff[k], sboff[k]+shist[k]); intersect
            // with this item's j-range. Sorted order => consecutive lanes
            // share a segment => near-uniform trip count.
            if (v0) {
                const int kk  = ki0 & (NBIN - 1);
                const int slo = sboff[kk], shi = slo + shist[kk];
                const int clo = max(slo, jlo), chi = min(shi, jhi);
                for (int j = clo; j < chi; ++j) {
                    const float d = pi0 - sval[j];
                    pull += relu_pull(d);
                    q    -= relu_push(d);
                }
            }
            if (v1) {
                const int kk  = ki1 & (NBIN - 1);
                const int slo = sboff[kk], shi = slo + shist[kk];
                const int clo = max(slo, jlo), chi = min(shi, jhi);
                for (int j = clo; j < chi; ++j) {
                    const float d = pi1 - sval[j];
                    pull += relu_pull(d);
                    q    -= relu_push(d);
                }
            }
            push += q;
        } else {
            // ---- comparison-based loop (arbitrary keys; cold) ------------
            for (int j = jlo; j < jhi; ++j) {
                const float v = sval[j]; const int kj = skey[j];
                {
                    const float d = fabsf(pi0 - v);
                    const bool  s = (ki0 == kj);
                    pull += s ? fmaxf(d - PULL_MARGIN, 0.f) : 0.f;
                    push += s ? 0.f : fmaxf(PUSH_MARGIN - d, 0.f);
                    cnt  += s ? 1 : 0;
                }
                {
                    const float d = fabsf(pi1 - v);
                    const bool  s = (ki1 == kj);
                    pull += s ? fmaxf(d - PULL_MARGIN, 0.f) : 0.f;
                    push += s ? 0.f : fmaxf(PUSH_MARGIN - d, 0.f);
                    cnt  += s ? 1 : 0;
                }
            }
        }
    }

    // -- ns: sorted path gets it from the histogram. ns_hist is
    //    BLOCK-UNIFORM, so exactly ONE thread of ONE block may inject it
    //    into the summing reduction (R2 bug: gating only on blockIdx.x
    //    summed it 256x). badkey path counts per-thread in the loop.
    int ns = badkey ? cnt : ((blockIdx.x == 0 && tid == 0) ? ns_hist : 0);

    // -- block reduction + agent-scope slot store. Words 0-2 relaxed,
    //    word 3 RELEASE so a single acquire-poll on word 3 suffices.
    #pragma unroll
    for (int off = 32; off > 0; off >>= 1) {
        pull += __shfl_down(pull, off);
        push += __shfl_down(push, off);
        ns   += __shfl_down(ns,   off);
    }
    if (lane == 0) { sredp[wv] = pull; sredq[wv] = push; sredn[wv] = ns; }
    __syncthreads();
    if (tid == 0) {
        float tp = 0.f, tq = 0.f; int tn = 0;
        #pragma unroll
        for (int w = 0; w < BLOCK / 64; ++w) {
            tp += sredp[w]; tq += sredq[w]; tn += sredn[w];
        }
        unsigned int* slot = partial + (size_t)(b * GRIDX + blockIdx.x) * 4;
        __hip_atomic_store(&slot[0], __float_as_uint(tp), __ATOMIC_RELAXED,
                           __HIP_MEMORY_SCOPE_AGENT);
        __hip_atomic_store(&slot[1], __float_as_uint(tq), __ATOMIC_RELAXED,
                           __HIP_MEMORY_SCOPE_AGENT);
        __hip_atomic_store(&slot[2], (unsigned int)tn, __ATOMIC_RELAXED,
                           __HIP_MEMORY_SCOPE_AGENT);
        __hip_atomic_store(&slot[3], (unsigned int)n, __ATOMIC_RELEASE,
                           __HIP_MEMORY_SCOPE_AGENT);
    }

    // -- finalizer: block (0,0) polls word 3 of all 256 slots (thread tid ->
    //    slot tid; wave w == sample w since GRIDX == 64). Acquire on word 3
    //    makes words 0-2 (released before it) visible with relaxed loads.
    if (blockIdx.x == 0 && blockIdx.y == 0) {
        unsigned int* slot = partial + (size_t)tid * 4;
        unsigned int w3;
        do { w3 = __hip_atomic_load(&slot[3], __ATOMIC_ACQUIRE,
                                    __HIP_MEMORY_SCOPE_AGENT); }
        while (w3 & 0x80000000u);
        const unsigned int w0 = __hip_atomic_load(&slot[0], __ATOMIC_RELAXED,
                                                  __HIP_MEMORY_SCOPE_AGENT);
        const unsigned int w1 = __hip_atomic_load(&slot[1], __ATOMIC_RELAXED,
                                                  __HIP_MEMORY_SCOPE_AGENT);
        const unsigned int w2 = __hip_atomic_load(&slot[2], __ATOMIC_RELAXED,
                                                  __HIP_MEMORY_SCOPE_AGENT);

        float fp = __uint_as_float(w0), fq = __uint_as_float(w1);
        int   fns = (int)w2;
        const int fn = (int)w3;                  // identical across a sample
        #pragma unroll
        for (int off = 32; off > 0; off >>= 1) {
            fp  += __shfl_down(fp,  off);
            fq  += __shfl_down(fq,  off);
            fns += __shfl_down(fns, off);
        }
        if (lane == 0) {
            const long nd = (long)fn * (long)fn - (long)fns;
            const float lp = fp / (float)(fns > 1 ? fns : 1);
            const float lq = (nd > 0) ? fq / (float)nd : 0.f;
            sloss[wv] = lp + lq;
        }
        __syncthreads();
        if (tid == 0)
            out[0] = (sloss[0] + sloss[1] + sloss[2] + sloss[3])
                     * (1.0f / (float)B_FIXED);
    }
}

// ============================ fallback path ================================
// Correct for any C/P (unused for this problem's fixed shapes).
#define TJ 256

__device__ __forceinline__ int detect_mask_mode_g(const void* mask, int P) {
    __shared__ int s_flags[2];
    const unsigned int* mw = (const unsigned int*)mask;
    unsigned int not01 = 0, notf01 = 0;
    for (int idx = threadIdx.x; idx < P; idx += blockDim.x) {
        unsigned int w = mw[idx];
        not01  |= (w > 1u) ? 1u : 0u;
        notf01 |= (w != 0u && w != 0x3f800000u) ? 1u : 0u;
    }
    if (threadIdx.x == 0) { s_flags[0] = 0; s_flags[1] = 0; }
    __syncthreads();
    if (not01)  atomicOr(&s_flags[0], 1);
    if (notf01) atomicOr(&s_flags[1], 1);
    __syncthreads();
    int mode;
    if (!s_flags[0])      mode = 0;
    else if (!s_flags[1]) mode = 2;
    else                  mode = 1;
    return mode;
}

__global__ __launch_bounds__(BLOCK)
void fallback_pair_kernel(const float* __restrict__ pred,
                          const int*   __restrict__ gt,
                          const void*  __restrict__ mask,
                          float* __restrict__ accF, int* __restrict__ nsI,
                          int* __restrict__ npI, int C, int P) {
    extern __shared__ char smem[];
    float* sval = (float*)smem;
    int*   skey = (int*)(sval + (long)C * TJ);
    __shared__ float sred[BLOCK / 64][2];
    __shared__ int   sredi[BLOCK / 64][2];

    const int b   = blockIdx.y;
    const int tid = threadIdx.x;
    const int mode = detect_mask_mode_g(mask, P);
    const long pixBase  = (long)b * P;
    const long predBase = (long)b * C * P;

    const int  i  = blockIdx.x * BLOCK + tid;
    int ki = -2;
    if (i < P) ki = read_fg(mask, mode, pixBase + i) ? gt[pixBase + i] : -2;
    const bool ifg = (ki >= 0);

    float pull = 0.f, push = 0.f;
    int ns = 0, np = 0;

    for (int j0 = 0; j0 < P; j0 += TJ) {
        __syncthreads();
        {
            const int j = j0 + tid;
            const bool v = j < P;
            bool fg = v ? read_fg(mask, mode, pixBase + j) : false;
            for (int c = 0; c < C; ++c)
                sval[c * TJ + tid] = v ? pred[predBase + (long)c * P + j] : -1e30f;
            skey[tid] = (v && fg) ? gt[pixBase + j] : -1;
        }
        __syncthreads();
        if (i < P) {
            for (int jj = 0; jj < TJ; ++jj) {
                float sq = 0.f;
                for (int c = 0; c < C; ++c) {
                    const float d = pred[predBase + (long)c * P + i] - sval[c * TJ + jj];
                    sq = fmaf(d, d, sq);
                }
                const float dist = sqrtf(sq);
                const int   kj = skey[jj];
                const bool  pm = ifg & (kj >= 0);
                const bool  s  = (ki == kj);
                pull += s ? fmaxf(dist - PULL_MARGIN, 0.f) : 0.f;
                push += (pm && !s) ? fmaxf(PUSH_MARGIN - dist, 0.f) : 0.f;
                ns   += s ? 1 : 0;
                np   += pm ? 1 : 0;
            }
        }
    }

    #pragma unroll
    for (int off = 32; off > 0; off >>= 1) {
        pull += __shfl_down(pull, off);
        push += __shfl_down(push, off);
        ns   += __shfl_down(ns,   off);
        np   += __shfl_down(np,   off);
    }
    const int wave = tid >> 6, lane = tid & 63;
    if (lane == 0) {
        sred[wave][0] = pull; sred[wave][1] = push;
        sredi[wave][0] = ns;  sredi[wave][1] = np;
    }
    __syncthreads();
    if (tid == 0) {
        float tp = 0.f, tq = 0.f; int tn = 0, tm = 0;
        #pragma unroll
        for (int w = 0; w < BLOCK / 64; ++w) {
            tp += sred[w][0]; tq += sred[w][1];
            tn += sredi[w][0]; tm += sredi[w][1];
        }
        atomicAdd(&accF[b * 4 + 0], tp);
        atomicAdd(&accF[b * 4 + 1], tq);
        atomicAdd(&nsI[b], tn);
        atomicAdd(&npI[b], tm);
    }
}

__global__ void finalize_fallback(const float* __restrict__ accF,
                                  const int* __restrict__ nsI,
                                  const int* __restrict__ npI,
                                  float* __restrict__ out) {
    if (threadIdx.x == 0 && blockIdx.x == 0) {
        float loss = 0.f;
        #pragma unroll
        for (int b = 0; b < B_FIXED; ++b) {
            const long ns = nsI[b];
            const long nd = (long)npI[b] - ns;
            const float pull = accF[b * 4 + 0] / (float)(ns > 1 ? ns : 1);
            const float push = (nd > 0) ? accF[b * 4 + 1] / (float)nd : 0.f;
            loss += pull + push;
        }
        out[0] = loss * (1.0f / (float)B_FIXED);
    }
}

extern "C" void kernel_launch(void* const* d_in, const int* in_sizes, int n_in,
                              void* d_out, int out_size, void* d_ws, size_t ws_size,
                              hipStream_t stream) {
    const float* pred = (const float*)d_in[0];
    const int*   gt   = (const int*)d_in[1];
    const void*  mask = d_in[2];
    float* out = (float*)d_out;

    const int C = in_sizes[0] / in_sizes[1];
    const int P = in_sizes[1] / B_FIXED;

    if (C == 1 && P == P_FIX && ws_size >= 4096) {
        // hot path: ONE dispatch, no memset, completion via poison-aware
        // slot polling in block (0,0).
        dim3 grid(GRIDX, B_FIXED);
        fused_all<<<grid, BLOCK, 0, stream>>>(pred, gt, mask,
                                              (unsigned int*)d_ws, out);
    } else {
        float* accF = (float*)((char*)d_ws + 4096);
        int*   nsI  = (int*)((char*)d_ws + 4096 + 128);
        int*   npI  = (int*)((char*)d_ws + 4096 + 192);
        hipMemsetAsync((char*)d_ws + 4096, 0, 512, stream);
        dim3 gF((P + BLOCK - 1) / BLOCK, B_FIXED);
        fallback_pair_kernel<<<gF, BLOCK, (size_t)(C + 1) * TJ * 4, stream>>>(
            pred, gt, mask, accF, nsI, npI, C, P);
        finalize_fallback<<<1, 64, 0, stream>>>(accF, nsI, npI, out);
    }
}

// Round 5
// 70.635 us; speedup vs baseline: 1.0100x; 1.0100x over previous
//
#include <hip/hip_runtime.h>

// Fixed by setup_inputs(): B=4, C=1, H=64, W=96 (P=6144).
// Hot path is specialized for C==1 && P==6144; anything else takes the
// slow-but-correct fallback.
#define B_FIXED 4
#define P_FIX   6144
#define BLOCK   256
#define NCH     (P_FIX / BLOCK)   // 24 register-resident chunks per thread
#define GRIDX   64                // blocks per sample
#define NJ      16                // j-range splits per i-tile
#define IBLK    2                 // i-rows per thread in the pair loop
#define NBIN    32                // key bins for counting sort (keys are 0..19)
#define PULL_MARGIN 0.5f
#define PUSH_MARGIN 1.0f

// ---- ws layout ------------------------------------------------------------
// Hot path : NONE. Each block knows the full-sample denominators from its
//            own redundant histogram (n = compaction count, ns = sum c_g^2),
//            so it atomicAdds its normalized contribution directly into
//            out[0] (harness zeroes out before launch). No slots, no poll,
//            no finalizer -- the cross-block protocol is gone.
// Fallback : accF/nsI/npI at offset 4096 (memset'd; cold path only).

// ---- bool-mask encoding detection ----------------------------------------
// mode 0: int32 {0,1}; mode 1: uint8 {0,1}; mode 2: float32 {0,1.0f}
__device__ __forceinline__ bool read_fg(const void* mask, int mode, long idx) {
    if (mode == 0) return ((const int*)mask)[idx] != 0;
    if (mode == 1) return ((const unsigned char*)mask)[idx] != 0;
    return ((const float*)mask)[idx] != 0.0f;
}

__device__ __forceinline__ float relu_push(float diff) {   // (1 - |diff|)+
    return fmaxf(PUSH_MARGIN - fabsf(diff), 0.0f);
}
__device__ __forceinline__ float relu_pull(float diff) {   // (|diff| - 0.5)+
    return fmaxf(fabsf(diff) - PULL_MARGIN, 0.0f);
}

// ---- single fused kernel (C==1, P==6144) ----------------------------------
// grid (GRIDX, B). Each block redundantly compacts sample b's foreground
// pixels into its own LDS, COUNTING-SORTED BY KEY, computes its share of
// pair terms, normalizes with its locally-known denominators, and does ONE
// device-scope atomicAdd into out[0]. loss = sum over blocks of
//   (pull_partial/max(ns,1) + (nd>0 ? push_partial/nd : 0)) / B
// which equals the reference (division distributes over the partial sums).
//
// Sorted layout enables a select-free pair loop:
//   push = sum_all (1-d)+  -  sum_own-key-segment (1-d)+
//   pull = sum_own-key-segment (d-0.5)+
//   n_same = sum_g count_g^2   (histogram; block-local, used only in the
//            denominator -- never enters a summing reduction)
// Any foreground key outside [0,NBIN) flips a block-uniform badkey flag:
// the comparison-based loop runs instead (data is permuted, which is fine:
// pair sums are permutation-invariant), and the block redundantly computes
// the full-sample ns itself (cold path; keeps blocks self-contained).
__global__ __launch_bounds__(BLOCK)
void fused_all(const float* __restrict__ pred,
               const int*   __restrict__ gt,
               const void*  __restrict__ mask,
               float* __restrict__ out) {
    __shared__ __align__(16) float sval[P_FIX];   // 24 KB (sorted values)
    __shared__ __align__(16) int   skey[P_FIX];   // 24 KB (sorted keys)
    __shared__ int   swdet[3 * (BLOCK / 64)];
    __shared__ int   shist[NBIN];   // per-key counts
    __shared__ int   sboff[NBIN];   // exclusive offsets (segment starts)
    __shared__ int   snext[NBIN];   // scatter cursors
    __shared__ int   smeta[3];      // n, ns_hist, badkey
    __shared__ float sredp[BLOCK / 64], sredq[BLOCK / 64];
    __shared__ int   sredn[BLOCK / 64];

    const int tid  = threadIdx.x;
    const int b    = blockIdx.y;
    const int wv   = tid >> 6, lane = tid & 63;
    const long base = (long)b * P_FIX;

    // -- single load wave: ALL independent global reads issued together.
    //    * detection words: first P_FIX words of the mask buffer (in-bounds
    //      for all three candidate encodings).
    //    * own-sample BYTE view of the mask (byte idx < B*P -> in-bounds
    //      for every encoding; only used if mode==1).
    //    * pred, gt.
    const unsigned int*  mw = (const unsigned int*)mask;
    const unsigned char* m8 = (const unsigned char*)mask;
    float val[NCH]; int key[NCH];
    unsigned int detA = 0, detC = 0, detN = 0, fgb = 0;
    #pragma unroll
    for (int k = 0; k < NCH; ++k) {
        const int idx = k * BLOCK + tid;
        const unsigned int w = mw[idx];
        detA |= (w > 1u) ? 1u : 0u;
        detC |= (w != 0u && w != 0x3f800000u) ? 1u : 0u;
        detN |= w;
        fgb  |= (m8[base + idx] != 0) ? (1u << k) : 0u;
        val[k] = pred[base + idx];
        key[k] = gt[base + idx];
    }
    const int anyA = (__ballot(detA != 0u) != 0ull) ? 1 : 0;
    const int anyC = (__ballot(detC != 0u) != 0ull) ? 1 : 0;
    const int anyN = (__ballot(detN != 0u) != 0ull) ? 1 : 0;
    if (lane == 0) {
        swdet[wv * 3 + 0] = anyA;
        swdet[wv * 3 + 1] = anyC;
        swdet[wv * 3 + 2] = anyN;
    }
    if (tid < NBIN) shist[tid] = 0;
    if (tid == 0)   smeta[2] = 0;
    __syncthreads();
    int fA = 0, fC = 0, fN = 0;
    #pragma unroll
    for (int w = 0; w < BLOCK / 64; ++w) {
        fA |= swdet[w * 3 + 0]; fC |= swdet[w * 3 + 1]; fN |= swdet[w * 3 + 2];
    }
    const int mode = (!fA) ? 0 : (!fC ? 2 : 1);

    // -- foreground bits. Entirely-zero mask (fN==0) short-circuits (also
    //    avoids the word-view reload, which would be OOB on a byte buffer).
    unsigned int fgm;
    if (!fN) {
        fgm = 0;
    } else if (mode == 1) {
        fgm = fgb;
    } else if (mode == 0) {
        fgm = 0;
        #pragma unroll
        for (int k = 0; k < NCH; ++k)
            fgm |= (((const int*)mask)[base + k * BLOCK + tid] != 0) ? (1u << k) : 0u;
    } else {
        fgm = 0;
        #pragma unroll
        for (int k = 0; k < NCH; ++k)
            fgm |= (((const float*)mask)[base + k * BLOCK + tid] != 0.0f) ? (1u << k) : 0u;
    }

    // -- histogram over foreground keys (bins clamped via &31; exact keys
    //    kept in registers -> badkey path still sees true keys).
    unsigned int badbit = 0;
    #pragma unroll
    for (int k = 0; k < NCH; ++k) {
        if ((fgm >> k) & 1u) {
            const int kk = key[k];
            badbit |= (unsigned int)(kk < 0 || kk >= NBIN);
            atomicAdd(&shist[kk & (NBIN - 1)], 1);
        }
    }
    if (badbit) atomicOr(&smeta[2], 1);
    __syncthreads();

    // -- wave 0: 32-bin exclusive scan + n + ns = sum(count^2)
    if (wv == 0) {
        const int c = (lane < NBIN) ? shist[lane] : 0;
        int incl = c;
        #pragma unroll
        for (int off = 1; off < NBIN; off <<= 1) {
            const int u = __shfl_up(incl, off);
            if (lane >= off) incl += u;
        }
        int sq = c * c;
        #pragma unroll
        for (int off = 1; off < NBIN; off <<= 1)
            sq += __shfl_xor(sq, off);
        const int ntot = __shfl(incl, NBIN - 1);
        if (lane < NBIN) { sboff[lane] = incl - c; snext[lane] = incl - c; }
        if (lane == 0)   { smeta[0] = ntot; smeta[1] = sq; }
    }
    __syncthreads();
    const int n       = smeta[0];
    const int ns_hist = smeta[1];
    const int badkey  = smeta[2];

    // -- atomic-rank scatter into sorted LDS arrays (rank order within a
    //    bin is arbitrary -- pair sums don't care).
    #pragma unroll
    for (int k = 0; k < NCH; ++k) {
        if ((fgm >> k) & 1u) {
            const int r = atomicAdd(&snext[key[k] & (NBIN - 1)], 1);
            sval[r] = val[k]; skey[r] = key[k];
        }
    }
    __syncthreads();

    // -- badkey (cold, block-uniform): histogram denominators are invalid
    //    (bin aliasing), so THIS block redundantly computes the full-sample
    //    n_same over all n^2 pairs. Keeps every block self-contained: no
    //    cross-block protocol even for mixed good/bad samples.
    int ns_bad = 0;   // meaningful on tid 0 only
    if (badkey) {
        int nsf = 0;
        for (int i = tid; i < n; i += BLOCK) {
            const int kif = skey[i];
            for (int j = 0; j < n; ++j) nsf += (kif == skey[j]) ? 1 : 0;
        }
        #pragma unroll
        for (int off = 32; off > 0; off >>= 1) nsf += __shfl_down(nsf, off);
        if (lane == 0) sredn[wv] = nsf;
        __syncthreads();
        if (tid == 0) {
            #pragma unroll
            for (int w = 0; w < BLOCK / 64; ++w) ns_bad += sredn[w];
        }
    }

    // -- pair loop: grid-stride over (i-tile, j-split) work items.
    //    i-tile = IBLK*BLOCK = 512 sorted rows; j-split = ~n/NJ columns.
    const int nti   = (n + IBLK * BLOCK - 1) / (IBLK * BLOCK);
    const int total = nti * NJ;
    float pull = 0.f, push = 0.f;

    for (int t = blockIdx.x; t < total; t += GRIDX) {
        const int it = t / NJ, jt = t - it * NJ;
        const int i0 = it * (IBLK * BLOCK) + tid;
        const int i1 = i0 + BLOCK;
        const bool v0 = i0 < n, v1 = i1 < n;
        const float pi0 = v0 ? sval[i0] : 1e30f;  // pad: push term -> 0
        const float pi1 = v1 ? sval[i1] : 1e30f;
        const int   ki0 = v0 ? skey[i0] : -2;     // pad: never 'same'
        const int   ki1 = v1 ? skey[i1] : -2;
        const int jlo = (jt == 0)      ? 0 : (int)(((long)jt * n / NJ) & ~3L);
        const int jhi = (jt == NJ - 1) ? n : (int)(((long)(jt + 1) * n / NJ) & ~3L);
        const int gve = jhi & ~3;                 // == jhi except last split

        if (!badkey) {
            // ---- select-free push-all over [jlo,jhi): 4 VALU per pair ----
            const float4* sv4 = (const float4*)sval;
            float q0 = 0.f, q1 = 0.f, q2 = 0.f, q3 = 0.f;
            #pragma unroll 2
            for (int g = (jlo >> 2); g < (gve >> 2); ++g) {
                const float4 v = sv4[g];
                q0 += relu_push(pi0 - v.x);
                q1 += relu_push(pi0 - v.y);
                q0 += relu_push(pi0 - v.z);
                q1 += relu_push(pi0 - v.w);
                q2 += relu_push(pi1 - v.x);
                q3 += relu_push(pi1 - v.y);
                q2 += relu_push(pi1 - v.z);
                q3 += relu_push(pi1 - v.w);
            }
            for (int j = gve; j < jhi; ++j) {     // scalar tail (last split)
                const float v = sval[j];
                q0 += relu_push(pi0 - v);
                q2 += relu_push(pi1 - v);
            }
            float q = (q0 + q1) + (q2 + q3);

            // ---- own-segment correction: pull + push fix-up --------------
            // Segment of key k is [sboff[k], sboff[k]+shist[k]); intersect
            // with this item's j-range. Sorted order => consecutive lanes
            // share a segment => near-uniform trip count.
            if (v0) {
                const int kk  = ki0 & (NBIN - 1);
                const int slo = sboff[kk], shi = slo + shist[kk];
                const int clo = max(slo, jlo), chi = min(shi, jhi);
                for (int j = clo; j < chi; ++j) {
                    const float d = pi0 - sval[j];
                    pull += relu_pull(d);
                    q    -= relu_push(d);
                }
            }
            if (v1) {
                const int kk  = ki1 & (NBIN - 1);
                const int slo = sboff[kk], shi = slo + shist[kk];
                const int clo = max(slo, jlo), chi = min(shi, jhi);
                for (int j = clo; j < chi; ++j) {
                    const float d = pi1 - sval[j];
                    pull += relu_pull(d);
                    q    -= relu_push(d);
                }
            }
            push += q;
        } else {
            // ---- comparison-based loop (arbitrary keys; cold) ------------
            for (int j = jlo; j < jhi; ++j) {
                const float v = sval[j]; const int kj = skey[j];
                {
                    const float d = fabsf(pi0 - v);
                    const bool  s = (ki0 == kj);
                    pull += s ? fmaxf(d - PULL_MARGIN, 0.f) : 0.f;
                    push += s ? 0.f : fmaxf(PUSH_MARGIN - d, 0.f);
                }
                {
                    const float d = fabsf(pi1 - v);
                    const bool  s = (ki1 == kj);
                    pull += s ? fmaxf(d - PULL_MARGIN, 0.f) : 0.f;
                    push += s ? 0.f : fmaxf(PUSH_MARGIN - d, 0.f);
                }
            }
        }
    }

    // -- block reduction, then ONE device-scope atomicAdd of this block's
    //    normalized contribution. Denominators are block-local knowledge:
    //    n (compaction count) and ns (histogram, or redundant count when
    //    badkey). out[] is zeroed by the harness before launch.
    #pragma unroll
    for (int off = 32; off > 0; off >>= 1) {
        pull += __shfl_down(pull, off);
        push += __shfl_down(push, off);
    }
    if (lane == 0) { sredp[wv] = pull; sredq[wv] = push; }
    __syncthreads();
    if (tid == 0) {
        float tp = 0.f, tq = 0.f;
        #pragma unroll
        for (int w = 0; w < BLOCK / 64; ++w) { tp += sredp[w]; tq += sredq[w]; }
        const int  ns = badkey ? ns_bad : ns_hist;
        const long nd = (long)n * (long)n - (long)ns;
        float contrib = tp / (float)(ns > 1 ? ns : 1);
        if (nd > 0) contrib += tq / (float)nd;
        atomicAdd(out, contrib * (1.0f / (float)B_FIXED));
    }
}

// ============================ fallback path ================================
// Correct for any C/P (unused for this problem's fixed shapes).
#define TJ 256

__device__ __forceinline__ int detect_mask_mode_g(const void* mask, int P) {
    __shared__ int s_flags[2];
    const unsigned int* mw = (const unsigned int*)mask;
    unsigned int not01 = 0, notf01 = 0;
    for (int idx = threadIdx.x; idx < P; idx += blockDim.x) {
        unsigned int w = mw[idx];
        not01  |= (w > 1u) ? 1u : 0u;
        notf01 |= (w != 0u && w != 0x3f800000u) ? 1u : 0u;
    }
    if (threadIdx.x == 0) { s_flags[0] = 0; s_flags[1] = 0; }
    __syncthreads();
    if (not01)  atomicOr(&s_flags[0], 1);
    if (notf01) atomicOr(&s_flags[1], 1);
    __syncthreads();
    int mode;
    if (!s_flags[0])      mode = 0;
    else if (!s_flags[1]) mode = 2;
    else                  mode = 1;
    return mode;
}

__global__ __launch_bounds__(BLOCK)
void fallback_pair_kernel(const float* __restrict__ pred,
                          const int*   __restrict__ gt,
                          const void*  __restrict__ mask,
                          float* __restrict__ accF, int* __restrict__ nsI,
                          int* __restrict__ npI, int C, int P) {
    extern __shared__ char smem[];
    float* sval = (float*)smem;
    int*   skey = (int*)(sval + (long)C * TJ);
    __shared__ float sred[BLOCK / 64][2];
    __shared__ int   sredi[BLOCK / 64][2];

    const int b   = blockIdx.y;
    const int tid = threadIdx.x;
    const int mode = detect_mask_mode_g(mask, P);
    const long pixBase  = (long)b * P;
    const long predBase = (long)b * C * P;

    const int  i  = blockIdx.x * BLOCK + tid;
    int ki = -2;
    if (i < P) ki = read_fg(mask, mode, pixBase + i) ? gt[pixBase + i] : -2;
    const bool ifg = (ki >= 0);

    float pull = 0.f, push = 0.f;
    int ns = 0, np = 0;

    for (int j0 = 0; j0 < P; j0 += TJ) {
        __syncthreads();
        {
            const int j = j0 + tid;
            const bool v = j < P;
            bool fg = v ? read_fg(mask, mode, pixBase + j) : false;
            for (int c = 0; c < C; ++c)
                sval[c * TJ + tid] = v ? pred[predBase + (long)c * P + j] : -1e30f;
            skey[tid] = (v && fg) ? gt[pixBase + j] : -1;
        }
        __syncthreads();
        if (i < P) {
            for (int jj = 0; jj < TJ; ++jj) {
                float sq = 0.f;
                for (int c = 0; c < C; ++c) {
                    const float d = pred[predBase + (long)c * P + i] - sval[c * TJ + jj];
                    sq = fmaf(d, d, sq);
                }
                const float dist = sqrtf(sq);
                const int   kj = skey[jj];
                const bool  pm = ifg & (kj >= 0);
                const bool  s  = (ki == kj);
                pull += s ? fmaxf(dist - PULL_MARGIN, 0.f) : 0.f;
                push += (pm && !s) ? fmaxf(PUSH_MARGIN - dist, 0.f) : 0.f;
                ns   += s ? 1 : 0;
                np   += pm ? 1 : 0;
            }
        }
    }

    #pragma unroll
    for (int off = 32; off > 0; off >>= 1) {
        pull += __shfl_down(pull, off);
        push += __shfl_down(push, off);
        ns   += __shfl_down(ns,   off);
        np   += __shfl_down(np,   off);
    }
    const int wave = tid >> 6, lane = tid & 63;
    if (lane == 0) {
        sred[wave][0] = pull; sred[wave][1] = push;
        sredi[wave][0] = ns;  sredi[wave][1] = np;
    }
    __syncthreads();
    if (tid == 0) {
        float tp = 0.f, tq = 0.f; int tn = 0, tm = 0;
        #pragma unroll
        for (int w = 0; w < BLOCK / 64; ++w) {
            tp += sred[w][0]; tq += sred[w][1];
            tn += sredi[w][0]; tm += sredi[w][1];
        }
        atomicAdd(&accF[b * 4 + 0], tp);
        atomicAdd(&accF[b * 4 + 1], tq);
        atomicAdd(&nsI[b], tn);
        atomicAdd(&npI[b], tm);
    }
}

__global__ void finalize_fallback(const float* __restrict__ accF,
                                  const int* __restrict__ nsI,
                                  const int* __restrict__ npI,
                                  float* __restrict__ out) {
    if (threadIdx.x == 0 && blockIdx.x == 0) {
        float loss = 0.f;
        #pragma unroll
        for (int b = 0; b < B_FIXED; ++b) {
            const long ns = nsI[b];
            const long nd = (long)npI[b] - ns;
            const float pull = accF[b * 4 + 0] / (float)(ns > 1 ? ns : 1);
            const float push = (nd > 0) ? accF[b * 4 + 1] / (float)nd : 0.f;
            loss += pull + push;
        }
        out[0] = loss * (1.0f / (float)B_FIXED);
    }
}

extern "C" void kernel_launch(void* const* d_in, const int* in_sizes, int n_in,
                              void* d_out, int out_size, void* d_ws, size_t ws_size,
                              hipStream_t stream) {
    const float* pred = (const float*)d_in[0];
    const int*   gt   = (const int*)d_in[1];
    const void*  mask = d_in[2];
    float* out = (float*)d_out;

    const int C = in_sizes[0] / in_sizes[1];
    const int P = in_sizes[1] / B_FIXED;

    if (C == 1 && P == P_FIX) {
        // hot path: ONE dispatch, no ws, no memset, no cross-block protocol.
        // Each block atomicAdds its normalized contribution into out[0]
        // (harness zeroes out before launch).
        dim3 grid(GRIDX, B_FIXED);
        fused_all<<<grid, BLOCK, 0, stream>>>(pred, gt, mask, out);
    } else {
        float* accF = (float*)((char*)d_ws + 4096);
        int*   nsI  = (int*)((char*)d_ws + 4096 + 128);
        int*   npI  = (int*)((char*)d_ws + 4096 + 192);
        hipMemsetAsync((char*)d_ws + 4096, 0, 512, stream);
        dim3 gF((P + BLOCK - 1) / BLOCK, B_FIXED);
        fallback_pair_kernel<<<gF, BLOCK, (size_t)(C + 1) * TJ * 4, stream>>>(
            pred, gt, mask, accF, nsI, npI, C, P);
        finalize_fallback<<<1, 64, 0, stream>>>(accF, nsI, npI, out);
    }
}